// Round 1
// baseline (471.183 us; speedup 1.0000x reference)
//
#include <hip/hip_runtime.h>
#include <stdint.h>

// ---------------------------------------------------------------------------
// QUIK quantized linear, M=N=K=4096.
//   out[b,o] = (dot(x_q[b,:], w_q[o,:]) + bias[o]) * sa * sw
//              + (xmin + 4*sa) * wsum[b]            (B == out quirk: row index)
// q-values in [-4,3] are exact in bf16; fp32 MFMA accumulation is exact.
// ---------------------------------------------------------------------------

using f32x4 = __attribute__((ext_vector_type(4))) float;
using s16x8 = __attribute__((ext_vector_type(8))) short;   // 8 bf16 (4 VGPRs)

#define TID ((int)threadIdx.x)

// Order-preserving float<->uint encoding for atomic min/max.
__device__ __forceinline__ unsigned encf(float f) {
  unsigned u = __float_as_uint(f);
  return (u & 0x80000000u) ? ~u : (u | 0x80000000u);
}
__device__ __forceinline__ float decf(unsigned u) {
  unsigned v = (u & 0x80000000u) ? (u & 0x7fffffffu) : ~u;
  return __uint_as_float(v);
}

__global__ void k_init(unsigned* mm) {
  mm[0] = 0xffffffffu;  // x min (encoded identity)
  mm[1] = 0u;           // x max
  mm[2] = 0xffffffffu;  // w min
  mm[3] = 0u;           // w max
}

// Grid-stride min/max over n4 float4s -> atomic into mm[0..1].
__global__ __launch_bounds__(256) void k_minmax(const float4* __restrict__ x,
                                                unsigned* __restrict__ mm, int n4) {
  float lmin = 1e30f, lmax = -1e30f;
  int stride = gridDim.x * 256;
  for (int i = blockIdx.x * 256 + TID; i < n4; i += stride) {
    float4 v = x[i];
    lmin = fminf(lmin, fminf(fminf(v.x, v.y), fminf(v.z, v.w)));
    lmax = fmaxf(lmax, fmaxf(fmaxf(v.x, v.y), fmaxf(v.z, v.w)));
  }
  __shared__ float smin[256], smax[256];
  smin[TID] = lmin; smax[TID] = lmax;
  __syncthreads();
  for (int s = 128; s > 0; s >>= 1) {
    if (TID < s) {
      smin[TID] = fminf(smin[TID], smin[TID + s]);
      smax[TID] = fmaxf(smax[TID], smax[TID + s]);
    }
    __syncthreads();
  }
  if (TID == 0) {
    atomicMin(&mm[0], encf(smin[0]));
    atomicMax(&mm[1], encf(smax[0]));
  }
}

// One block per weight row: row sum + contribute to global w min/max.
__global__ __launch_bounds__(256) void k_rowred(const float4* __restrict__ w,
                                                unsigned* __restrict__ mmw,
                                                float* __restrict__ wsum) {
  int row = blockIdx.x;
  const float4* wr = w + (size_t)row * 1024;
  float lmin = 1e30f, lmax = -1e30f, lsum = 0.f;
  for (int c = TID; c < 1024; c += 256) {
    float4 v = wr[c];
    lmin = fminf(lmin, fminf(fminf(v.x, v.y), fminf(v.z, v.w)));
    lmax = fmaxf(lmax, fmaxf(fmaxf(v.x, v.y), fmaxf(v.z, v.w)));
    lsum += (v.x + v.y) + (v.z + v.w);
  }
  __shared__ float smin[256], smax[256], ssum[256];
  smin[TID] = lmin; smax[TID] = lmax; ssum[TID] = lsum;
  __syncthreads();
  for (int s = 128; s > 0; s >>= 1) {
    if (TID < s) {
      smin[TID] = fminf(smin[TID], smin[TID + s]);
      smax[TID] = fmaxf(smax[TID], smax[TID + s]);
      ssum[TID] += ssum[TID + s];
    }
    __syncthreads();
  }
  if (TID == 0) {
    wsum[row] = ssum[0];
    atomicMin(&mmw[0], encf(smin[0]));
    atomicMax(&mmw[1], encf(smax[0]));
  }
}

// Quantize: bit-exact replication of np fp32 ops, emit bf16 bits of integer q.
__device__ __forceinline__ unsigned q1(float t, float zero, float scale) {
  float v = (t - zero) / scale - 4.0f;   // IEEE div, matches np
  v = fminf(3.0f, fmaxf(-4.0f, v));
  float f = (float)(int)v;               // trunc toward zero == astype(int32)
  return __float_as_uint(f) >> 16;       // exact bf16 for ints in [-4,3]
}

__global__ __launch_bounds__(256) void k_quant(const float4* __restrict__ in,
                                               uint4* __restrict__ outq,
                                               const unsigned* __restrict__ mm, int off) {
  float zero = decf(mm[off]);
  float scale = (decf(mm[off + 1]) - zero) * 0.125f;  // (max-min)/8, /8 exact
  int idx = blockIdx.x * 256 + TID;
  float4 a = in[(size_t)idx * 2];
  float4 b = in[(size_t)idx * 2 + 1];
  uint4 o;
  o.x = q1(a.x, zero, scale) | (q1(a.y, zero, scale) << 16);
  o.y = q1(a.z, zero, scale) | (q1(a.w, zero, scale) << 16);
  o.z = q1(b.x, zero, scale) | (q1(b.y, zero, scale) << 16);
  o.w = q1(b.z, zero, scale) | (q1(b.w, zero, scale) << 16);
  outq[idx] = o;
}

__device__ __forceinline__ void gload_lds16(const short* g, short* l) {
  __builtin_amdgcn_global_load_lds(
      (__attribute__((address_space(1))) void*)(g),
      (__attribute__((address_space(3))) void*)(l), 16, 0, 0);
}

// 128x128 tile per 256-thread block, BK=64, 4 waves each 64x64 (4x4 MFMA tiles).
// m97-style: global_load_lds width=16 staging, ds_read_b128 fragments.
__global__ __launch_bounds__(256) void k_gemm(const short* __restrict__ Xq,
                                              const short* __restrict__ Wq,
                                              const float* __restrict__ bias,
                                              const float* __restrict__ wsum,
                                              const unsigned* __restrict__ mm,
                                              float* __restrict__ out) {
  __shared__ __align__(16) short As[128 * 64];
  __shared__ __align__(16) short Bs[128 * 64];

  const int tid = TID;
  const int bx = blockIdx.x, by = blockIdx.y;
  const int lane = tid & 63, wave = tid >> 6;
  const int wm = (wave >> 1) * 64, wn = (wave & 1) * 64;
  const int r = lane & 15, qd = lane >> 4;

  // Staging: thread t loads 16B = 8 bf16 from row (issue*32 + t/8), col8 (t&7).
  const short* gA = Xq + ((size_t)(by * 128 + (tid >> 3))) * 4096 + ((tid & 7) * 8);
  const short* gB = Wq + ((size_t)(bx * 128 + (tid >> 3))) * 4096 + ((tid & 7) * 8);
  short* lA = As + tid * 8;   // wave-uniform base + lane*16B (required pattern)
  short* lB = Bs + tid * 8;

  // Fragment base: A[m = wm+i*16+r][k = kk + qd*8 .. +8], row-major stride 64.
  const s16x8* a8 = (const s16x8*)(As) + (wm + r) * 8 + qd;
  const s16x8* b8 = (const s16x8*)(Bs) + (wn + r) * 8 + qd;

  f32x4 acc[4][4];
#pragma unroll
  for (int i = 0; i < 4; ++i)
#pragma unroll
    for (int j = 0; j < 4; ++j) acc[i][j] = (f32x4){0.f, 0.f, 0.f, 0.f};

  for (int k0 = 0; k0 < 4096; k0 += 64) {
#pragma unroll
    for (int s = 0; s < 4; ++s) {
      gload_lds16(gA + (size_t)s * 32 * 4096, lA + s * 2048);
      gload_lds16(gB + (size_t)s * 32 * 4096, lB + s * 2048);
    }
    gA += 64; gB += 64;
    __syncthreads();   // drains vmcnt for global_load_lds

#pragma unroll
    for (int kk8 = 0; kk8 < 8; kk8 += 4) {  // two K=32 chunks
      s16x8 af[4], bf[4];
#pragma unroll
      for (int i = 0; i < 4; ++i) af[i] = a8[i * 128 + kk8];
#pragma unroll
      for (int j = 0; j < 4; ++j) bf[j] = b8[j * 128 + kk8];
#pragma unroll
      for (int i = 0; i < 4; ++i)
#pragma unroll
        for (int j = 0; j < 4; ++j)
          acc[i][j] = __builtin_amdgcn_mfma_f32_16x16x32_bf16(af[i], bf[j], acc[i][j], 0, 0, 0);
    }
    __syncthreads();
  }

  // Epilogue: C/D layout col = lane&15, row = qd*4 + reg.
  float xmin = decf(mm[0]), xmax = decf(mm[1]);
  float wmin = decf(mm[2]), wmax = decf(mm[3]);
  float sa = (xmax - xmin) * 0.125f;
  float sw = (wmax - wmin) * 0.125f;
  float mid = xmin + 4.0f * sa;

  int col0 = bx * 128 + wn + r;
  float bcol[4];
#pragma unroll
  for (int j = 0; j < 4; ++j) bcol[j] = bias[col0 + j * 16];
  int row0 = by * 128 + wm + qd * 4;
#pragma unroll
  for (int i = 0; i < 4; ++i) {
#pragma unroll
    for (int rr = 0; rr < 4; ++rr) {
      int row = row0 + i * 16 + rr;
      float sh = mid * wsum[row];
      float* po = out + (size_t)row * 4096 + col0;
#pragma unroll
      for (int j = 0; j < 4; ++j) {
        po[j * 16] = (acc[i][j][rr] + bcol[j]) * sa * sw + sh;  // ref op order
      }
    }
  }
}

extern "C" void kernel_launch(void* const* d_in, const int* in_sizes, int n_in,
                              void* d_out, int out_size, void* d_ws, size_t ws_size,
                              hipStream_t stream) {
  (void)in_sizes; (void)n_in; (void)out_size; (void)ws_size;
  const float* x = (const float*)d_in[0];
  const float* w = (const float*)d_in[1];
  const float* bias = (const float*)d_in[2];
  float* out = (float*)d_out;

  char* ws = (char*)d_ws;
  unsigned* mm = (unsigned*)ws;                       // 4 encoded scalars
  float* wsum = (float*)(ws + 256);                   // 4096 floats
  short* Xq = (short*)(ws + 32768);                   // 4096x4096 bf16 (33.5 MB)
  short* Wq = (short*)(ws + 32768 + (size_t)33554432);// 4096x4096 bf16 (33.5 MB)

  k_init<<<1, 1, 0, stream>>>(mm);
  k_minmax<<<1024, 256, 0, stream>>>((const float4*)x, mm, 4096 * 4096 / 4);
  k_rowred<<<4096, 256, 0, stream>>>((const float4*)w, mm + 2, wsum);
  k_quant<<<8192, 256, 0, stream>>>((const float4*)x, (uint4*)Xq, mm, 0);
  k_quant<<<8192, 256, 0, stream>>>((const float4*)w, (uint4*)Wq, mm, 2);
  dim3 g(32, 32);
  k_gemm<<<g, 256, 0, stream>>>(Xq, Wq, bias, wsum, mm, out);
}

// Round 2
// 338.561 us; speedup vs baseline: 1.3917x; 1.3917x over previous
//
#include <hip/hip_runtime.h>
#include <stdint.h>

// ---------------------------------------------------------------------------
// QUIK quantized linear, M=N=K=4096.
//   out[b,o] = (dot(x_q[b,:], w_q[o,:]) + bias[o]) * sa * sw
//              + (xmin + 4*sa) * wsum[b]            (B == out quirk: row index)
// Round 2: int8 MFMA (q in [-4,3] exact in i8, int32 dot exact) +
// XOR-swizzled LDS (conflict-free ds_read_b128 with unpadded global_load_lds).
// ---------------------------------------------------------------------------

using i32x4 = __attribute__((ext_vector_type(4))) int;

#define TID ((int)threadIdx.x)

// Order-preserving float<->uint encoding for atomic min/max.
__device__ __forceinline__ unsigned encf(float f) {
  unsigned u = __float_as_uint(f);
  return (u & 0x80000000u) ? ~u : (u | 0x80000000u);
}
__device__ __forceinline__ float decf(unsigned u) {
  unsigned v = (u & 0x80000000u) ? (u & 0x7fffffffu) : ~u;
  return __uint_as_float(v);
}

__global__ void k_init(unsigned* mm) {
  mm[0] = 0xffffffffu;  // x min (encoded identity)
  mm[1] = 0u;           // x max
  mm[2] = 0xffffffffu;  // w min
  mm[3] = 0u;           // w max
}

// Fused stats: blocks 0..4095 -> weight row b (sum + min/max);
//              blocks 4096..5119 -> grid-stride x min/max.
__global__ __launch_bounds__(256) void k_stats(const float4* __restrict__ x,
                                               const float4* __restrict__ w,
                                               unsigned* __restrict__ mm,
                                               float* __restrict__ wsum) {
  __shared__ float smin[256], smax[256], ssum[256];
  float lmin = 1e30f, lmax = -1e30f, lsum = 0.f;
  bool isw = (blockIdx.x < 4096);
  if (isw) {
    const float4* wr = w + (size_t)blockIdx.x * 1024;
#pragma unroll
    for (int c = 0; c < 4; ++c) {
      float4 v = wr[c * 256 + TID];
      lmin = fminf(lmin, fminf(fminf(v.x, v.y), fminf(v.z, v.w)));
      lmax = fmaxf(lmax, fmaxf(fmaxf(v.x, v.y), fmaxf(v.z, v.w)));
      lsum += (v.x + v.y) + (v.z + v.w);
    }
  } else {
    int base = (blockIdx.x - 4096) * 256 + TID;
    for (int i = base; i < 4096 * 1024; i += 1024 * 256) {
      float4 v = x[i];
      lmin = fminf(lmin, fminf(fminf(v.x, v.y), fminf(v.z, v.w)));
      lmax = fmaxf(lmax, fmaxf(fmaxf(v.x, v.y), fmaxf(v.z, v.w)));
    }
  }
  smin[TID] = lmin; smax[TID] = lmax; ssum[TID] = lsum;
  __syncthreads();
  for (int s = 128; s > 0; s >>= 1) {
    if (TID < s) {
      smin[TID] = fminf(smin[TID], smin[TID + s]);
      smax[TID] = fmaxf(smax[TID], smax[TID + s]);
      ssum[TID] += ssum[TID + s];
    }
    __syncthreads();
  }
  if (TID == 0) {
    if (isw) {
      wsum[blockIdx.x] = ssum[0];
      atomicMin(&mm[2], encf(smin[0]));
      atomicMax(&mm[3], encf(smax[0]));
    } else {
      atomicMin(&mm[0], encf(smin[0]));
      atomicMax(&mm[1], encf(smax[0]));
    }
  }
}

// Quantize: bit-exact replication of np fp32 ops -> int8.
__device__ __forceinline__ int q1i(float t, float zero, float scale) {
  float v = (t - zero) / scale - 4.0f;   // IEEE div, matches np
  v = fminf(3.0f, fmaxf(-4.0f, v));
  return (int)v;                         // trunc toward zero == astype(int32)
}

__device__ __forceinline__ unsigned pack4(float4 v, float zero, float scale) {
  return (q1i(v.x, zero, scale) & 255) | ((q1i(v.y, zero, scale) & 255) << 8) |
         ((q1i(v.z, zero, scale) & 255) << 16) | ((q1i(v.w, zero, scale) & 255) << 24);
}

// Fused quant: blocks 0..4095 -> x row b -> Xq; 4096..8191 -> w row -> Wq.
// Thread t: 16 consecutive elements -> one uint4 store.
__global__ __launch_bounds__(256) void k_quant(const float4* __restrict__ x,
                                               const float4* __restrict__ w,
                                               uint4* __restrict__ Xq,
                                               uint4* __restrict__ Wq,
                                               const unsigned* __restrict__ mm) {
  bool isx = (blockIdx.x < 4096);
  int row = isx ? blockIdx.x : (blockIdx.x - 4096);
  const float4* in = (isx ? x : w) + (size_t)row * 1024 + TID * 4;
  uint4* outq = (isx ? Xq : Wq) + (size_t)row * 256 + TID;
  float zero = decf(mm[isx ? 0 : 2]);
  float scale = (decf(mm[isx ? 1 : 3]) - zero) * 0.125f;  // (max-min)/8 exact
  float4 a = in[0], b = in[1], c = in[2], d = in[3];
  uint4 o;
  o.x = pack4(a, zero, scale);
  o.y = pack4(b, zero, scale);
  o.z = pack4(c, zero, scale);
  o.w = pack4(d, zero, scale);
  *outq = o;
}

__device__ __forceinline__ void gload_lds16(const char* g, char* l) {
  __builtin_amdgcn_global_load_lds(
      (__attribute__((address_space(1))) void*)(g),
      (__attribute__((address_space(3))) void*)(l), 16, 0, 0);
}

// 128x128 tile per 256-thread block, BK=128 i8, 4 waves each 64x64 (4x4 MFMA
// tiles of 16x16x64_i8). LDS rows are 128 B = 8 x 16-B chunks = 32 banks;
// physical chunk pc in row holds logical chunk pc ^ (row&7) (XOR swizzle via
// the staging *source* address -> conflict-free ds_read_b128, no padding).
__global__ __launch_bounds__(256) void k_gemm(const char* __restrict__ Xq,
                                              const char* __restrict__ Wq,
                                              const float* __restrict__ bias,
                                              const float* __restrict__ wsum,
                                              const unsigned* __restrict__ mm,
                                              float* __restrict__ out) {
  __shared__ __align__(16) char As[128 * 128];  // 16 KB
  __shared__ __align__(16) char Bs[128 * 128];  // 16 KB

  const int tid = TID;
  const int bx = blockIdx.x, by = blockIdx.y;
  const int lane = tid & 63, wave = tid >> 6;
  const int wm = (wave >> 1) * 64, wn = (wave & 1) * 64;
  const int r = lane & 15, qd = lane >> 4;

  // Staging: thread t, issue s -> LDS bytes (s*256+t)*16 = row s*32+t/8,
  // physical chunk t&7, which must hold logical chunk (t&7)^((t>>3)&7).
  const int lc = (tid & 7) ^ ((tid >> 3) & 7);
  const char* gA = Xq + (size_t)(by * 128 + (tid >> 3)) * 4096 + lc * 16;
  const char* gB = Wq + (size_t)(bx * 128 + (tid >> 3)) * 4096 + lc * 16;
  char* lA = As + tid * 16;
  char* lB = Bs + tid * 16;

  // Fragment chunk index helper: logical chunk kk*4+qd, swizzled by r&7.
  const int swzA0 = (qd) ^ (r & 7);      // kk=0
  const int swzA1 = (4 + qd) ^ (r & 7);  // kk=1

  i32x4 acc[4][4];
#pragma unroll
  for (int i = 0; i < 4; ++i)
#pragma unroll
    for (int j = 0; j < 4; ++j) acc[i][j] = (i32x4){0, 0, 0, 0};

  const i32x4* As4 = (const i32x4*)As;
  const i32x4* Bs4 = (const i32x4*)Bs;

  for (int k0 = 0; k0 < 4096; k0 += 128) {
#pragma unroll
    for (int s = 0; s < 4; ++s) {
      gload_lds16(gA + (size_t)s * 32 * 4096, lA + s * 4096);
      gload_lds16(gB + (size_t)s * 32 * 4096, lB + s * 4096);
    }
    gA += 128; gB += 128;
    __syncthreads();  // drains vmcnt for global_load_lds

#pragma unroll
    for (int kk = 0; kk < 2; ++kk) {
      const int swz = kk ? swzA1 : swzA0;
      i32x4 af[4], bf[4];
#pragma unroll
      for (int i = 0; i < 4; ++i) af[i] = As4[(wm + i * 16 + r) * 8 + swz];
#pragma unroll
      for (int j = 0; j < 4; ++j) bf[j] = Bs4[(wn + j * 16 + r) * 8 + swz];
#pragma unroll
      for (int i = 0; i < 4; ++i)
#pragma unroll
        for (int j = 0; j < 4; ++j)
          acc[i][j] = __builtin_amdgcn_mfma_i32_16x16x64_i8(af[i], bf[j], acc[i][j], 0, 0, 0);
    }
    __syncthreads();
  }

  // Epilogue: C/D layout col = lane&15, row = qd*4 + reg (shape-determined).
  float xmin = decf(mm[0]), xmax = decf(mm[1]);
  float wmin = decf(mm[2]), wmax = decf(mm[3]);
  float sa = (xmax - xmin) * 0.125f;
  float sw = (wmax - wmin) * 0.125f;
  float mid = xmin + 4.0f * sa;

  int col0 = bx * 128 + wn + r;
  float bcol[4];
#pragma unroll
  for (int j = 0; j < 4; ++j) bcol[j] = bias[col0 + j * 16];
  int row0 = by * 128 + wm + qd * 4;
#pragma unroll
  for (int i = 0; i < 4; ++i) {
#pragma unroll
    for (int rr = 0; rr < 4; ++rr) {
      int row = row0 + i * 16 + rr;
      float sh = mid * wsum[row];
      float* po = out + (size_t)row * 4096 + col0;
#pragma unroll
      for (int j = 0; j < 4; ++j) {
        po[j * 16] = ((float)acc[i][j][rr] + bcol[j]) * sa * sw + sh;  // ref op order
      }
    }
  }
}

extern "C" void kernel_launch(void* const* d_in, const int* in_sizes, int n_in,
                              void* d_out, int out_size, void* d_ws, size_t ws_size,
                              hipStream_t stream) {
  (void)in_sizes; (void)n_in; (void)out_size; (void)ws_size;
  const float* x = (const float*)d_in[0];
  const float* w = (const float*)d_in[1];
  const float* bias = (const float*)d_in[2];
  float* out = (float*)d_out;

  char* ws = (char*)d_ws;
  unsigned* mm = (unsigned*)ws;                        // 4 encoded scalars
  float* wsum = (float*)(ws + 256);                    // 4096 floats
  char* Xq = ws + 32768;                               // 4096x4096 i8 (16.8 MB)
  char* Wq = ws + 32768 + (size_t)16777216;            // 4096x4096 i8 (16.8 MB)

  k_init<<<1, 1, 0, stream>>>(mm);
  k_stats<<<5120, 256, 0, stream>>>((const float4*)x, (const float4*)w, mm, wsum);
  k_quant<<<8192, 256, 0, stream>>>((const float4*)x, (const float4*)w,
                                    (uint4*)Xq, (uint4*)Wq, mm);
  dim3 g(32, 32);
  k_gemm<<<g, 256, 0, stream>>>(Xq, Wq, bias, wsum, mm, out);
}

// Round 3
// 263.628 us; speedup vs baseline: 1.7873x; 1.2842x over previous
//
#include <hip/hip_runtime.h>
#include <stdint.h>

// ---------------------------------------------------------------------------
// QUIK quantized linear, M=N=K=4096.
//   out[b,o] = (dot(x_q[b,:], w_q[o,:]) + bias[o]) * sa * sw
//              + (xmin + 4*sa) * wsum[b]            (B == out quirk: row index)
// Round 3: balanced atomic-free stats + final-reduce; GEMM on
// mfma_i32_32x32x32_i8 (2x2 tiles/wave) to double MACs per ds_read_b128.
// ---------------------------------------------------------------------------

using i32x4  = __attribute__((ext_vector_type(4))) int;
using i32x16 = __attribute__((ext_vector_type(16))) int;

#define TID ((int)threadIdx.x)

// ---------------- stats: 8192 blocks, 16 KB each, no atomics ---------------
// blocks 0..4095   -> weight row b: min/max/sum
// blocks 4096..8191-> x chunk (b-4096): min/max
// partials: pmin[blk], pmax[blk]; wsum[row] direct.
__global__ __launch_bounds__(256) void k_stats(const float4* __restrict__ x,
                                               const float4* __restrict__ w,
                                               float* __restrict__ pmin,
                                               float* __restrict__ pmax,
                                               float* __restrict__ wsum) {
  const int blk = blockIdx.x;
  const bool isw = blk < 4096;
  const float4* src = isw ? (w + (size_t)blk * 1024)
                          : (x + (size_t)(blk - 4096) * 1024);
  float4 v0 = src[TID], v1 = src[256 + TID], v2 = src[512 + TID], v3 = src[768 + TID];
  float lmin = fminf(fminf(fminf(v0.x, v0.y), fminf(v0.z, v0.w)),
                     fminf(fminf(v1.x, v1.y), fminf(v1.z, v1.w)));
  lmin = fminf(lmin, fminf(fminf(fminf(v2.x, v2.y), fminf(v2.z, v2.w)),
                           fminf(fminf(v3.x, v3.y), fminf(v3.z, v3.w))));
  float lmax = fmaxf(fmaxf(fmaxf(v0.x, v0.y), fmaxf(v0.z, v0.w)),
                     fmaxf(fmaxf(v1.x, v1.y), fmaxf(v1.z, v1.w)));
  lmax = fmaxf(lmax, fmaxf(fmaxf(fmaxf(v2.x, v2.y), fmaxf(v2.z, v2.w)),
                           fmaxf(fmaxf(v3.x, v3.y), fmaxf(v3.z, v3.w))));
  float lsum = ((v0.x + v0.y) + (v0.z + v0.w)) + ((v1.x + v1.y) + (v1.z + v1.w)) +
               ((v2.x + v2.y) + (v2.z + v2.w)) + ((v3.x + v3.y) + (v3.z + v3.w));

#pragma unroll
  for (int d = 32; d > 0; d >>= 1) {
    lmin = fminf(lmin, __shfl_down(lmin, d));
    lmax = fmaxf(lmax, __shfl_down(lmax, d));
    lsum += __shfl_down(lsum, d);
  }
  __shared__ float smn[4], smx[4], ssm[4];
  const int wv = TID >> 6;
  if ((TID & 63) == 0) { smn[wv] = lmin; smx[wv] = lmax; ssm[wv] = lsum; }
  __syncthreads();
  if (TID == 0) {
    float mn = fminf(fminf(smn[0], smn[1]), fminf(smn[2], smn[3]));
    float mx = fmaxf(fmaxf(smx[0], smx[1]), fmaxf(smx[2], smx[3]));
    pmin[blk] = mn; pmax[blk] = mx;
    if (isw) wsum[blk] = (ssm[0] + ssm[1]) + (ssm[2] + ssm[3]);
  }
}

// Single block: reduce 8192 partials -> mmf = {xmin, xmax, wmin, wmax}.
__global__ __launch_bounds__(256) void k_final(const float* __restrict__ pmin,
                                               const float* __restrict__ pmax,
                                               float* __restrict__ mmf) {
  float wmn = 1e30f, wmx = -1e30f, xmn = 1e30f, xmx = -1e30f;
  for (int i = TID; i < 4096; i += 256) {
    wmn = fminf(wmn, pmin[i]);        wmx = fmaxf(wmx, pmax[i]);
    xmn = fminf(xmn, pmin[4096 + i]); xmx = fmaxf(xmx, pmax[4096 + i]);
  }
#pragma unroll
  for (int d = 32; d > 0; d >>= 1) {
    xmn = fminf(xmn, __shfl_down(xmn, d));
    xmx = fmaxf(xmx, __shfl_down(xmx, d));
    wmn = fminf(wmn, __shfl_down(wmn, d));
    wmx = fmaxf(wmx, __shfl_down(wmx, d));
  }
  __shared__ float s[4][4];
  const int wv = TID >> 6;
  if ((TID & 63) == 0) { s[wv][0] = xmn; s[wv][1] = xmx; s[wv][2] = wmn; s[wv][3] = wmx; }
  __syncthreads();
  if (TID == 0) {
    mmf[0] = fminf(fminf(s[0][0], s[1][0]), fminf(s[2][0], s[3][0]));
    mmf[1] = fmaxf(fmaxf(s[0][1], s[1][1]), fmaxf(s[2][1], s[3][1]));
    mmf[2] = fminf(fminf(s[0][2], s[1][2]), fminf(s[2][2], s[3][2]));
    mmf[3] = fmaxf(fmaxf(s[0][3], s[1][3]), fmaxf(s[2][3], s[3][3]));
  }
}

// ---------------- quant: bit-exact np fp32 op replication -> int8 ----------
__device__ __forceinline__ int q1i(float t, float zero, float scale) {
  float v = (t - zero) / scale - 4.0f;   // IEEE div, matches np
  v = fminf(3.0f, fmaxf(-4.0f, v));
  return (int)v;                         // trunc toward zero == astype(int32)
}

__device__ __forceinline__ unsigned pack4(float4 v, float zero, float scale) {
  return (q1i(v.x, zero, scale) & 255) | ((q1i(v.y, zero, scale) & 255) << 8) |
         ((q1i(v.z, zero, scale) & 255) << 16) | ((q1i(v.w, zero, scale) & 255) << 24);
}

// blocks 0..4095 -> x row -> Xq; 4096..8191 -> w row -> Wq.
__global__ __launch_bounds__(256) void k_quant(const float4* __restrict__ x,
                                               const float4* __restrict__ w,
                                               uint4* __restrict__ Xq,
                                               uint4* __restrict__ Wq,
                                               const float* __restrict__ mmf) {
  bool isx = (blockIdx.x < 4096);
  int row = isx ? blockIdx.x : (blockIdx.x - 4096);
  const float4* in = (isx ? x : w) + (size_t)row * 1024 + TID * 4;
  uint4* outq = (isx ? Xq : Wq) + (size_t)row * 256 + TID;
  float zero = isx ? mmf[0] : mmf[2];
  float scale = ((isx ? mmf[1] : mmf[3]) - zero) * 0.125f;  // (max-min)/8 exact
  float4 a = in[0], b = in[1], c = in[2], d = in[3];
  uint4 o;
  o.x = pack4(a, zero, scale);
  o.y = pack4(b, zero, scale);
  o.z = pack4(c, zero, scale);
  o.w = pack4(d, zero, scale);
  *outq = o;
}

__device__ __forceinline__ void gload_lds16(const char* g, char* l) {
  __builtin_amdgcn_global_load_lds(
      (__attribute__((address_space(1))) void*)(g),
      (__attribute__((address_space(3))) void*)(l), 16, 0, 0);
}

// ---------------- GEMM: 128x128 tile, BK=128 i8, mfma_i32_32x32x32_i8 ------
// 4 waves each 64x64 = 2x2 tiles of 32x32. LDS rows 128 B = 8 x 16-B chunks;
// physical chunk pc of row holds logical chunk pc ^ (row&7) (swizzle applied
// on the staging *source* address -> conflict-free ds_read_b128, no padding).
// A-frag: lane holds A[row = wm+i*32+(lane&31)][k = kt*32 + (lane>>5)*16 + j].
// C/D (verified m74/m101): col = lane&31, row = (reg&3) + 8*(reg>>2) + 4*(lane>>5).
__global__ __launch_bounds__(256) void k_gemm(const char* __restrict__ Xq,
                                              const char* __restrict__ Wq,
                                              const float* __restrict__ bias,
                                              const float* __restrict__ wsum,
                                              const float* __restrict__ mmf,
                                              float* __restrict__ out) {
  __shared__ __align__(16) char As[128 * 128];  // 16 KB
  __shared__ __align__(16) char Bs[128 * 128];  // 16 KB

  const int tid = TID;
  const int bx = blockIdx.x, by = blockIdx.y;
  const int lane = tid & 63, wave = tid >> 6;
  const int wm = (wave >> 1) * 64, wn = (wave & 1) * 64;
  const int c5 = lane & 31, h = lane >> 5, s7 = c5 & 7;

  // Staging: thread t, issue s -> LDS bytes (s*256+t)*16 = row s*32+t/8,
  // physical chunk t&7, which must hold logical chunk (t&7)^((t>>3)&7).
  const int lc = (tid & 7) ^ ((tid >> 3) & 7);
  const char* gA = Xq + (size_t)(by * 128 + (tid >> 3)) * 4096 + lc * 16;
  const char* gB = Wq + (size_t)(bx * 128 + (tid >> 3)) * 4096 + lc * 16;
  char* lA = As + tid * 16;
  char* lB = Bs + tid * 16;

  const i32x4* As4 = (const i32x4*)As;
  const i32x4* Bs4 = (const i32x4*)Bs;

  i32x16 acc[2][2];
#pragma unroll
  for (int i = 0; i < 2; ++i)
#pragma unroll
    for (int j = 0; j < 2; ++j)
#pragma unroll
      for (int e = 0; e < 16; ++e) acc[i][j][e] = 0;

  for (int k0 = 0; k0 < 4096; k0 += 128) {
#pragma unroll
    for (int s = 0; s < 4; ++s) {
      gload_lds16(gA + (size_t)s * 32 * 4096, lA + s * 4096);
      gload_lds16(gB + (size_t)s * 32 * 4096, lB + s * 4096);
    }
    gA += 128; gB += 128;
    __syncthreads();  // drains vmcnt for global_load_lds

#pragma unroll
    for (int kt = 0; kt < 4; ++kt) {
      const int ch = (kt * 2 + h) ^ s7;
      i32x4 af[2], bf[2];
      af[0] = As4[(wm + c5) * 8 + ch];
      af[1] = As4[(wm + 32 + c5) * 8 + ch];
      bf[0] = Bs4[(wn + c5) * 8 + ch];
      bf[1] = Bs4[(wn + 32 + c5) * 8 + ch];
#pragma unroll
      for (int i = 0; i < 2; ++i)
#pragma unroll
        for (int j = 0; j < 2; ++j)
          acc[i][j] = __builtin_amdgcn_mfma_i32_32x32x32_i8(af[i], bf[j], acc[i][j], 0, 0, 0);
    }
    __syncthreads();
  }

  // Epilogue
  float sa = (mmf[1] - mmf[0]) * 0.125f;
  float sw = (mmf[3] - mmf[2]) * 0.125f;
  float mid = mmf[0] + 4.0f * sa;

  const int col0 = bx * 128 + wn + c5;
  const float b0 = bias[col0], b1 = bias[col0 + 32];
#pragma unroll
  for (int i = 0; i < 2; ++i) {
    const int rbase = by * 128 + wm + i * 32 + 4 * h;
#pragma unroll
    for (int g = 0; g < 4; ++g) {
#pragma unroll
      for (int q = 0; q < 4; ++q) {
        const int row = rbase + 8 * g + q;
        const float sh = mid * wsum[row];
        float* po = out + (size_t)row * 4096 + col0;
        po[0]  = ((float)acc[i][0][g * 4 + q] + b0) * sa * sw + sh;  // ref op order
        po[32] = ((float)acc[i][1][g * 4 + q] + b1) * sa * sw + sh;
      }
    }
  }
}

extern "C" void kernel_launch(void* const* d_in, const int* in_sizes, int n_in,
                              void* d_out, int out_size, void* d_ws, size_t ws_size,
                              hipStream_t stream) {
  (void)in_sizes; (void)n_in; (void)out_size; (void)ws_size;
  const float* x = (const float*)d_in[0];
  const float* w = (const float*)d_in[1];
  const float* bias = (const float*)d_in[2];
  float* out = (float*)d_out;

  char* ws = (char*)d_ws;
  float* mmf = (float*)ws;                             // 4 floats: xmin,xmax,wmin,wmax
  float* wsum = (float*)(ws + 1024);                   // 4096 floats
  float* pmin = (float*)(ws + 32768);                  // 8192 floats
  float* pmax = (float*)(ws + 65536);                  // 8192 floats
  char* Xq = ws + 131072;                              // 4096x4096 i8 (16.8 MB)
  char* Wq = ws + 131072 + (size_t)16777216;           // 4096x4096 i8 (16.8 MB)

  k_stats<<<8192, 256, 0, stream>>>((const float4*)x, (const float4*)w, pmin, pmax, wsum);
  k_final<<<1, 256, 0, stream>>>(pmin, pmax, mmf);
  k_quant<<<8192, 256, 0, stream>>>((const float4*)x, (const float4*)w,
                                    (uint4*)Xq, (uint4*)Wq, mmf);
  dim3 g(32, 32);
  k_gemm<<<g, 256, 0, stream>>>(Xq, Wq, bias, wsum, mmf, out);
}

// Round 4
// 253.699 us; speedup vs baseline: 1.8573x; 1.0391x over previous
//
#include <hip/hip_runtime.h>
#include <stdint.h>

// ---------------------------------------------------------------------------
// QUIK quantized linear, M=N=K=4096.
//   out[b,o] = (dot(x_q[b,:], w_q[o,:]) + bias[o]) * sa * sw
//              + (xmin + 4*sa) * wsum[b]            (B == out quirk: row index)
// Round 4: wave tile 128x64 (4x2 of mfma_i32_32x32x32_i8), block 256x128,
// 512 blocks = exactly 2/CU. MACs per LDS-read-byte 32 -> 42.7.
// ---------------------------------------------------------------------------

using i32x4  = __attribute__((ext_vector_type(4))) int;
using i32x16 = __attribute__((ext_vector_type(16))) int;

#define TID ((int)threadIdx.x)

// ---------------- stats: 8192 blocks, 16 KB each, no atomics ---------------
__global__ __launch_bounds__(256) void k_stats(const float4* __restrict__ x,
                                               const float4* __restrict__ w,
                                               float* __restrict__ pmin,
                                               float* __restrict__ pmax,
                                               float* __restrict__ wsum) {
  const int blk = blockIdx.x;
  const bool isw = blk < 4096;
  const float4* src = isw ? (w + (size_t)blk * 1024)
                          : (x + (size_t)(blk - 4096) * 1024);
  float4 v0 = src[TID], v1 = src[256 + TID], v2 = src[512 + TID], v3 = src[768 + TID];
  float lmin = fminf(fminf(fminf(v0.x, v0.y), fminf(v0.z, v0.w)),
                     fminf(fminf(v1.x, v1.y), fminf(v1.z, v1.w)));
  lmin = fminf(lmin, fminf(fminf(fminf(v2.x, v2.y), fminf(v2.z, v2.w)),
                           fminf(fminf(v3.x, v3.y), fminf(v3.z, v3.w))));
  float lmax = fmaxf(fmaxf(fmaxf(v0.x, v0.y), fmaxf(v0.z, v0.w)),
                     fmaxf(fmaxf(v1.x, v1.y), fmaxf(v1.z, v1.w)));
  lmax = fmaxf(lmax, fmaxf(fmaxf(fmaxf(v2.x, v2.y), fmaxf(v2.z, v2.w)),
                           fmaxf(fmaxf(v3.x, v3.y), fmaxf(v3.z, v3.w))));
  float lsum = ((v0.x + v0.y) + (v0.z + v0.w)) + ((v1.x + v1.y) + (v1.z + v1.w)) +
               ((v2.x + v2.y) + (v2.z + v2.w)) + ((v3.x + v3.y) + (v3.z + v3.w));

#pragma unroll
  for (int d = 32; d > 0; d >>= 1) {
    lmin = fminf(lmin, __shfl_down(lmin, d));
    lmax = fmaxf(lmax, __shfl_down(lmax, d));
    lsum += __shfl_down(lsum, d);
  }
  __shared__ float smn[4], smx[4], ssm[4];
  const int wv = TID >> 6;
  if ((TID & 63) == 0) { smn[wv] = lmin; smx[wv] = lmax; ssm[wv] = lsum; }
  __syncthreads();
  if (TID == 0) {
    float mn = fminf(fminf(smn[0], smn[1]), fminf(smn[2], smn[3]));
    float mx = fmaxf(fmaxf(smx[0], smx[1]), fmaxf(smx[2], smx[3]));
    pmin[blk] = mn; pmax[blk] = mx;
    if (isw) wsum[blk] = (ssm[0] + ssm[1]) + (ssm[2] + ssm[3]);
  }
}

// Single block: reduce 8192 partials -> mmf = {xmin, xmax, wmin, wmax}.
__global__ __launch_bounds__(256) void k_final(const float* __restrict__ pmin,
                                               const float* __restrict__ pmax,
                                               float* __restrict__ mmf) {
  float wmn = 1e30f, wmx = -1e30f, xmn = 1e30f, xmx = -1e30f;
  for (int i = TID; i < 4096; i += 256) {
    wmn = fminf(wmn, pmin[i]);        wmx = fmaxf(wmx, pmax[i]);
    xmn = fminf(xmn, pmin[4096 + i]); xmx = fmaxf(xmx, pmax[4096 + i]);
  }
#pragma unroll
  for (int d = 32; d > 0; d >>= 1) {
    xmn = fminf(xmn, __shfl_down(xmn, d));
    xmx = fmaxf(xmx, __shfl_down(xmx, d));
    wmn = fminf(wmn, __shfl_down(wmn, d));
    wmx = fmaxf(wmx, __shfl_down(wmx, d));
  }
  __shared__ float s[4][4];
  const int wv = TID >> 6;
  if ((TID & 63) == 0) { s[wv][0] = xmn; s[wv][1] = xmx; s[wv][2] = wmn; s[wv][3] = wmx; }
  __syncthreads();
  if (TID == 0) {
    mmf[0] = fminf(fminf(s[0][0], s[1][0]), fminf(s[2][0], s[3][0]));
    mmf[1] = fmaxf(fmaxf(s[0][1], s[1][1]), fmaxf(s[2][1], s[3][1]));
    mmf[2] = fminf(fminf(s[0][2], s[1][2]), fminf(s[2][2], s[3][2]));
    mmf[3] = fmaxf(fmaxf(s[0][3], s[1][3]), fmaxf(s[2][3], s[3][3]));
  }
}

// ---------------- quant: bit-exact np fp32 op replication -> int8 ----------
__device__ __forceinline__ int q1i(float t, float zero, float scale) {
  float v = (t - zero) / scale - 4.0f;   // IEEE div, matches np
  v = fminf(3.0f, fmaxf(-4.0f, v));
  return (int)v;                         // trunc toward zero == astype(int32)
}

__device__ __forceinline__ unsigned pack4(float4 v, float zero, float scale) {
  return (q1i(v.x, zero, scale) & 255) | ((q1i(v.y, zero, scale) & 255) << 8) |
         ((q1i(v.z, zero, scale) & 255) << 16) | ((q1i(v.w, zero, scale) & 255) << 24);
}

__global__ __launch_bounds__(256) void k_quant(const float4* __restrict__ x,
                                               const float4* __restrict__ w,
                                               uint4* __restrict__ Xq,
                                               uint4* __restrict__ Wq,
                                               const float* __restrict__ mmf) {
  bool isx = (blockIdx.x < 4096);
  int row = isx ? blockIdx.x : (blockIdx.x - 4096);
  const float4* in = (isx ? x : w) + (size_t)row * 1024 + TID * 4;
  uint4* outq = (isx ? Xq : Wq) + (size_t)row * 256 + TID;
  float zero = isx ? mmf[0] : mmf[2];
  float scale = ((isx ? mmf[1] : mmf[3]) - zero) * 0.125f;  // (max-min)/8 exact
  float4 a = in[0], b = in[1], c = in[2], d = in[3];
  uint4 o;
  o.x = pack4(a, zero, scale);
  o.y = pack4(b, zero, scale);
  o.z = pack4(c, zero, scale);
  o.w = pack4(d, zero, scale);
  *outq = o;
}

__device__ __forceinline__ void gload_lds16(const char* g, char* l) {
  __builtin_amdgcn_global_load_lds(
      (__attribute__((address_space(1))) void*)(g),
      (__attribute__((address_space(3))) void*)(l), 16, 0, 0);
}

// ---------------- GEMM: block 256x128, BK=128 i8, wave tile 128x64 ---------
// 4 waves: wave w -> rows (w>>1)*128..+127, cols (w&1)*64..+63; 4x2 tiles of
// mfma_i32_32x32x32_i8. LDS rows 128 B = 8 x 16-B chunks; physical chunk pc
// of row holds logical chunk pc ^ (row&7) (swizzle on staging source addr).
// A-frag (HW-verified r3): lane holds A[row=wm+i*32+(lane&31)][k=kt*32+(lane>>5)*16+j].
// C/D (verified m74/m101): col = lane&31, row = (reg&3) + 8*(reg>>2) + 4*(lane>>5).
__global__ __launch_bounds__(256, 2) void k_gemm(const char* __restrict__ Xq,
                                                 const char* __restrict__ Wq,
                                                 const float* __restrict__ bias,
                                                 const float* __restrict__ wsum,
                                                 const float* __restrict__ mmf,
                                                 float* __restrict__ out) {
  __shared__ __align__(16) char As[256 * 128];  // 32 KB
  __shared__ __align__(16) char Bs[128 * 128];  // 16 KB

  const int tid = TID;
  const int bx = blockIdx.x, by = blockIdx.y;
  const int lane = tid & 63, wave = tid >> 6;
  const int wm = (wave >> 1) * 128, wn = (wave & 1) * 64;
  const int c5 = lane & 31, h = lane >> 5, s7 = c5 & 7;

  // Staging: thread t, issue s -> LDS row s*32 + t/8, physical chunk t&7,
  // which must hold logical chunk (t&7)^((t>>3)&7).
  const int lc = (tid & 7) ^ ((tid >> 3) & 7);
  const char* gA = Xq + (size_t)(by * 256 + (tid >> 3)) * 4096 + lc * 16;
  const char* gB = Wq + (size_t)(bx * 128 + (tid >> 3)) * 4096 + lc * 16;
  char* lA = As + tid * 16;
  char* lB = Bs + tid * 16;

  const i32x4* As4 = (const i32x4*)As;
  const i32x4* Bs4 = (const i32x4*)Bs;

  i32x16 acc[4][2];
#pragma unroll
  for (int i = 0; i < 4; ++i)
#pragma unroll
    for (int j = 0; j < 2; ++j)
#pragma unroll
      for (int e = 0; e < 16; ++e) acc[i][j][e] = 0;

  for (int k0 = 0; k0 < 4096; k0 += 128) {
#pragma unroll
    for (int s = 0; s < 8; ++s)
      gload_lds16(gA + (size_t)s * 32 * 4096, lA + s * 4096);
#pragma unroll
    for (int s = 0; s < 4; ++s)
      gload_lds16(gB + (size_t)s * 32 * 4096, lB + s * 4096);
    gA += 128; gB += 128;
    __syncthreads();  // drains vmcnt for global_load_lds

#pragma unroll
    for (int kt = 0; kt < 4; ++kt) {
      const int ch = (kt * 2 + h) ^ s7;
      i32x4 af[4], bf[2];
#pragma unroll
      for (int i = 0; i < 4; ++i) af[i] = As4[(wm + i * 32 + c5) * 8 + ch];
#pragma unroll
      for (int j = 0; j < 2; ++j) bf[j] = Bs4[(wn + j * 32 + c5) * 8 + ch];
#pragma unroll
      for (int i = 0; i < 4; ++i)
#pragma unroll
        for (int j = 0; j < 2; ++j)
          acc[i][j] = __builtin_amdgcn_mfma_i32_32x32x32_i8(af[i], bf[j], acc[i][j], 0, 0, 0);
    }
    __syncthreads();
  }

  // Epilogue
  float sa = (mmf[1] - mmf[0]) * 0.125f;
  float sw = (mmf[3] - mmf[2]) * 0.125f;
  float mid = mmf[0] + 4.0f * sa;

  const int col0 = bx * 128 + wn + c5;
  const float b0 = bias[col0], b1 = bias[col0 + 32];
#pragma unroll
  for (int i = 0; i < 4; ++i) {
    const int rbase = by * 256 + wm + i * 32 + 4 * h;
#pragma unroll
    for (int g = 0; g < 4; ++g) {
#pragma unroll
      for (int q = 0; q < 4; ++q) {
        const int row = rbase + 8 * g + q;
        const float sh = mid * wsum[row];
        float* po = out + (size_t)row * 4096 + col0;
        po[0]  = ((float)acc[i][0][g * 4 + q] + b0) * sa * sw + sh;  // ref op order
        po[32] = ((float)acc[i][1][g * 4 + q] + b1) * sa * sw + sh;
      }
    }
  }
}

extern "C" void kernel_launch(void* const* d_in, const int* in_sizes, int n_in,
                              void* d_out, int out_size, void* d_ws, size_t ws_size,
                              hipStream_t stream) {
  (void)in_sizes; (void)n_in; (void)out_size; (void)ws_size;
  const float* x = (const float*)d_in[0];
  const float* w = (const float*)d_in[1];
  const float* bias = (const float*)d_in[2];
  float* out = (float*)d_out;

  char* ws = (char*)d_ws;
  float* mmf = (float*)ws;                             // 4 floats: xmin,xmax,wmin,wmax
  float* wsum = (float*)(ws + 1024);                   // 4096 floats
  float* pmin = (float*)(ws + 32768);                  // 8192 floats
  float* pmax = (float*)(ws + 65536);                  // 8192 floats
  char* Xq = ws + 131072;                              // 4096x4096 i8 (16.8 MB)
  char* Wq = ws + 131072 + (size_t)16777216;           // 4096x4096 i8 (16.8 MB)

  k_stats<<<8192, 256, 0, stream>>>((const float4*)x, (const float4*)w, pmin, pmax, wsum);
  k_final<<<1, 256, 0, stream>>>(pmin, pmax, mmf);
  k_quant<<<8192, 256, 0, stream>>>((const float4*)x, (const float4*)w,
                                    (uint4*)Xq, (uint4*)Wq, mmf);
  dim3 g(32, 16);
  k_gemm<<<g, 256, 0, stream>>>(Xq, Wq, bias, wsum, mmf, out);
}